// Round 10
// baseline (767.754 us; speedup 1.0000x reference)
//
#include <hip/hip_runtime.h>
#include <math.h>

// Shapes: B=3200, L=7, H=8, E=64, S=56, D=64, N=50
// queries [B,7,8,64], keys [B,56,8,64], values [B,56,8,64], mask [50,7,56]
// out [B,7,8,64] fp32.
//
// ONE DEEP MEMORY BATCH PER UNIT. R1-R9 post-mortems: delivered HBM BW only
// rises when demand rises (R7), so the cap is per-wave demand generation.
// The hidden serializer was Q: 112 uniform loads/unit (s_load chain, SGPR
// pegged at 112) in every prior round. Here ALL per-unit memory issues as
// one batch in consumption order: K(14 dwordx4) -> Q(7 dword) -> mask(7)
// -> V[0:28); K cvt+LDS (vmcnt waits K only); V[28:56); Q->LDS fp16.
// Scores/PV then run entirely from LDS/registers: K via lane-row swizzled
// b128, Q via uniform-broadcast b128 (7 loads replace 112). launch_bounds
// (64,3) gives the VGPR headroom (~170) to keep K+V batches live; ~8
// waves/CU with ~60 loads in flight each = MLP via ILP, not TLP.
// P transposed through dead K LDS; no-max softmax (scores bounded);
// deferred normalization.

typedef __attribute__((ext_vector_type(8))) _Float16 half8;

static __device__ __forceinline__ half8 cvt8(const float4 a, const float4 b) {
    half8 h;
    h[0] = (_Float16)a.x; h[1] = (_Float16)a.y;
    h[2] = (_Float16)a.z; h[3] = (_Float16)a.w;
    h[4] = (_Float16)b.x; h[5] = (_Float16)b.y;
    h[6] = (_Float16)b.z; h[7] = (_Float16)b.w;
    return h;
}

__launch_bounds__(64, 3)
__global__ void fullattn_kernel(const float* __restrict__ q,
                                const float* __restrict__ k,
                                const float* __restrict__ v,
                                const float* __restrict__ mask,
                                float* __restrict__ out,
                                int nstations) {
    __shared__ __align__(16) _Float16 KL[56 * 64];  // 7168 B; fp32 P overlays later
    __shared__ __align__(16) _Float16 QL[7 * 64];   // 896 B

    const int lane = threadIdx.x;     // 0..63
    const int unit = blockIdx.x;
    const int b    = unit >> 3;
    const int h    = unit & 7;
    const int st   = b % nstations;

    const int kbase = b * 28672 + h * 64;  // keys/values
    const int qbase = b * 3584  + h * 64;  // queries/out

    // ================= phase A: issue ALL memory, consumption order ========
    // A1: K, 14x global_load_dwordx4 (coalesced 1KB each)
    float4 kr0[7], kr1[7];
#pragma unroll
    for (int i = 0; i < 7; ++i) {
        const int f = i * 64 + lane;
        const int s = f >> 3;
        const int c = f & 7;
        kr0[i] = *(const float4*)(k + kbase + s * 512 + c * 8);
        kr1[i] = *(const float4*)(k + kbase + s * 512 + c * 8 + 4);
    }
    // A2: Q, 7x global_load_dword (e = lane) — replaces 112 uniform loads
    float qr[7];
#pragma unroll
    for (int l = 0; l < 7; ++l) qr[l] = q[qbase + l * 512 + lane];
    // A3: mask, 7x dword
    const int ml = (lane < 56) ? lane : 55;  // clamped s index
    float m[7];
#pragma unroll
    for (int l = 0; l < 7; ++l)
        m[l] = mask[st * 392 + l * 56 + ml] * 0.125f;  // scale = 1/sqrt(64)
    // A4: V rows 0..27 (lane = d)
    float vr[56];
#pragma unroll
    for (int i = 0; i < 28; ++i) vr[i] = v[kbase + i * 512 + lane];

    // ================= phase B: K cvt + LDS write (waits K only) ===========
    // slot f = i*64+lane: row s=f>>3, chunk c=f&7; physical chunk = c^(s&7)
#pragma unroll
    for (int i = 0; i < 7; ++i) {
        const int f = i * 64 + lane;
        const int s = f >> 3;
        const int c = f & 7;
        *(half8*)(&KL[s * 64 + 8 * (c ^ (s & 7))]) = cvt8(kr0[i], kr1[i]);
    }
    // V rows 28..55 (issued after K regs retire)
#pragma unroll
    for (int i = 28; i < 56; ++i) vr[i] = v[kbase + i * 512 + lane];
    // Q -> LDS fp16 (2-byte writes, 2 lanes/bank = free)
#pragma unroll
    for (int l = 0; l < 7; ++l) QL[l * 64 + lane] = (_Float16)qr[l];

    // ================= scores: lane = s, LDS only ==========================
    const int sx = ml & 7;  // XOR swizzle key
    float acc[7];
#pragma unroll
    for (int l = 0; l < 7; ++l) acc[l] = 0.0f;

#pragma unroll
    for (int c = 0; c < 8; ++c) {
        const half8 kv = *(const half8*)(&KL[ml * 64 + 8 * (c ^ sx)]);
#pragma unroll
        for (int l = 0; l < 7; ++l) {
            const half8 qv = *(const half8*)(&QL[l * 64 + c * 8]);  // uniform bcast
#pragma unroll
            for (int j = 0; j < 8; ++j)
                acc[l] = fmaf((float)qv[j], (float)kv[j], acc[l]);  // v_fma_mix
        }
    }

    // ======== softmax across lanes (s), no max-subtraction (bounded) =======
    // P (fp32) transposed into dead K buffer; per-wave in-order DS pipe.
    float* pbuf = (float*)KL;
    float rdenom[7];
#pragma unroll
    for (int l = 0; l < 7; ++l) {
        const float sc = acc[l] * m[l];
        const float p  = (lane < 56) ? __expf(sc) : 0.0f;
        float sum = p;
#pragma unroll
        for (int off = 32; off >= 1; off >>= 1)
            sum += __shfl_xor(sum, off);
        pbuf[l * 64 + lane] = p;
        rdenom[l] = __builtin_amdgcn_rcpf(sum);
    }

    // ================= PV: lane = d, V from registers ======================
    float facc[7];
#pragma unroll
    for (int l = 0; l < 7; ++l) facc[l] = 0.0f;

#pragma unroll
    for (int s4 = 0; s4 < 14; ++s4) {
#pragma unroll
        for (int l = 0; l < 7; ++l) {
            const float4 p4 = *(const float4*)(&pbuf[l * 64 + s4 * 4]);  // uniform bcast
            facc[l] = fmaf(p4.x, vr[s4 * 4 + 0], facc[l]);
            facc[l] = fmaf(p4.y, vr[s4 * 4 + 1], facc[l]);
            facc[l] = fmaf(p4.z, vr[s4 * 4 + 2], facc[l]);
            facc[l] = fmaf(p4.w, vr[s4 * 4 + 3], facc[l]);
        }
    }

    // ================= epilogue: deferred normalization + store ============
#pragma unroll
    for (int l = 0; l < 7; ++l)
        out[qbase + l * 512 + lane] = facc[l] * rdenom[l];
}

extern "C" void kernel_launch(void* const* d_in, const int* in_sizes, int n_in,
                              void* d_out, int out_size, void* d_ws, size_t ws_size,
                              hipStream_t stream) {
    const float* q    = (const float*)d_in[0];
    const float* k    = (const float*)d_in[1];
    const float* v    = (const float*)d_in[2];
    const float* mask = (const float*)d_in[3];
    float* out        = (float*)d_out;

    const int B = in_sizes[0] / (7 * 8 * 64);        // 3200
    const int nstations = in_sizes[3] / (7 * 56);    // 50

    fullattn_kernel<<<dim3(B * 8), dim3(64), 0, stream>>>(q, k, v, mask, out, nstations);
}

// Round 11
// 160.600 us; speedup vs baseline: 4.7805x; 4.7805x over previous
//
#include <hip/hip_runtime.h>
#include <math.h>

// Shapes: B=3200, L=7, H=8, E=64, S=56, D=64, N=50
// queries [B,7,8,64], keys [B,56,8,64], values [B,56,8,64], mask [50,7,56]
// out [B,7,8,64] fp32.
//
// DMA-STAGED K AND V (global_load_lds). R1-R10 lesson: the register
// allocator never keeps big load batches live (re-rolls at 44-84 VGPR,
// spills when forced), so per-wave memory-level parallelism collapsed to
// ~1 outstanding load. global_load_lds keeps 28 KB in flight per wave with
// ZERO register cost. Issue order (sched_barrier-pinned):
//   K-DMA(14x1KB, fp32, chunk-XOR pre-swizzled source)  [oldest]
//   Q(7 dword) -> mask(7 dword) -> V-DMA(14x1KB, linear)
// The QL-write's compiler-auto vmcnt gates scores on K+Q only; V stays in
// flight through scores+softmax; single manual vmcnt(0) before PV.
// Scores: lane=s, K b128 reads bank-balanced by XOR, Q uniform-broadcast
// fp16 from QL. Softmax: shuffle, no max-subtraction (scores bounded),
// P fp32 overlays dead K. PV: lane=d, V b32 (2-way free) x P uniform b128.
// LDS 29.6 KB -> 5 blocks/CU; 5 waves x 28KB DMA in flight >> BW-saturation
// requirement; registers ~60 so nothing can spill.

typedef __attribute__((ext_vector_type(8))) _Float16 half8;

#define GLDS(gp, lp) __builtin_amdgcn_global_load_lds(                        \
    (const __attribute__((address_space(1))) void*)(gp),                      \
    (__attribute__((address_space(3))) void*)(lp), 16, 0, 0)

__launch_bounds__(64, 4)
__global__ void fullattn_kernel(const float* __restrict__ q,
                                const float* __restrict__ k,
                                const float* __restrict__ v,
                                const float* __restrict__ mask,
                                float* __restrict__ out,
                                int nstations) {
    __shared__ __align__(16) float    KL[56 * 64];   // 14336 B; P overlays after scores
    __shared__ __align__(16) float    VL[56 * 64];   // 14336 B
    __shared__ __align__(16) _Float16 QL[7 * 64];    // 896 B

    const int lane = threadIdx.x;     // 0..63
    const int unit = blockIdx.x;
    const int b    = unit >> 3;
    const int h    = unit & 7;
    const int st   = b % nstations;

    const int kbase = b * 28672 + h * 64;  // keys/values
    const int qbase = b * 3584  + h * 64;  // queries/out

    // ---- issue group 1: K DMA, fp32, chunk-XOR pre-swizzled source ----
    // DMA j writes LDS floats [j*256,(j+1)*256): row r=4j+(lane>>4), slot
    // p=lane&15. Physical slot p must hold logical chunk c = p ^ (r&15)
    // so score reads at (c ^ (s&15)) are bank-balanced (7 lanes/group).
    {
        const int r = (lane >> 4);      // +4j below
        const int p = lane & 15;
#pragma unroll
        for (int j = 0; j < 14; ++j) {
            const int row = j * 4 + r;
            const int c   = p ^ (row & 15);
            GLDS(k + kbase + row * 512 + c * 4, (char*)KL + j * 1024);
        }
    }
    __builtin_amdgcn_sched_barrier(0);

    // ---- issue group 2: Q (7 dwords, e=lane) ----
    float qr[7];
#pragma unroll
    for (int l = 0; l < 7; ++l) qr[l] = q[qbase + l * 512 + lane];
    __builtin_amdgcn_sched_barrier(0);

    // ---- issue group 3: mask (7 dwords, pre-scaled) ----
    const int ml = (lane < 56) ? lane : 55;  // clamped s index
    float m[7];
#pragma unroll
    for (int l = 0; l < 7; ++l)
        m[l] = mask[st * 392 + l * 56 + ml] * 0.125f;  // scale = 1/sqrt(64)
    __builtin_amdgcn_sched_barrier(0);

    // ---- issue group 4: V DMA, linear layout ----
    {
        const int r = (lane >> 4);
        const int p = lane & 15;
#pragma unroll
        for (int j = 0; j < 14; ++j) {
            const int row = j * 4 + r;
            GLDS(v + kbase + row * 512 + p * 4, (char*)VL + j * 1024);
        }
    }
    __builtin_amdgcn_sched_barrier(0);

    // ---- fence: K done (oldest 14 of 42); blocks KL-read hoisting ----
    asm volatile("s_waitcnt vmcnt(28)" ::: "memory");
    __builtin_amdgcn_sched_barrier(0);

    // ---- Q -> LDS fp16 (compiler auto-waits qr: vmcnt(21) -> K+Q done) ----
#pragma unroll
    for (int l = 0; l < 7; ++l) QL[l * 64 + lane] = (_Float16)qr[l];

    // ---- scores: lane = s, K fp32 b128 (XOR slots) x Q fp16 uniform ----
    const int x16 = ml & 15;
    float acc[7];
#pragma unroll
    for (int l = 0; l < 7; ++l) acc[l] = 0.0f;

#pragma unroll
    for (int c2 = 0; c2 < 8; ++c2) {
        const float4 kv0 = *(const float4*)(&KL[ml * 64 + (((2 * c2)     ^ x16) << 2)]);
        const float4 kv1 = *(const float4*)(&KL[ml * 64 + (((2 * c2 + 1) ^ x16) << 2)]);
#pragma unroll
        for (int l = 0; l < 7; ++l) {
            const half8 qv = *(const half8*)(&QL[l * 64 + c2 * 8]);  // uniform bcast
            acc[l] = fmaf(kv0.x, (float)qv[0], acc[l]);
            acc[l] = fmaf(kv0.y, (float)qv[1], acc[l]);
            acc[l] = fmaf(kv0.z, (float)qv[2], acc[l]);
            acc[l] = fmaf(kv0.w, (float)qv[3], acc[l]);
            acc[l] = fmaf(kv1.x, (float)qv[4], acc[l]);
            acc[l] = fmaf(kv1.y, (float)qv[5], acc[l]);
            acc[l] = fmaf(kv1.z, (float)qv[6], acc[l]);
            acc[l] = fmaf(kv1.w, (float)qv[7], acc[l]);
        }
    }

    // ---- softmax (no max-subtraction; scores bounded); P overlays K ----
    // compiler auto-waits mask here (vmcnt(14)); V still in flight.
    float* pbuf = (float*)KL;
    float rdenom[7];
#pragma unroll
    for (int l = 0; l < 7; ++l) {
        const float sc = acc[l] * m[l];
        const float p  = (lane < 56) ? __expf(sc) : 0.0f;
        float sum = p;
#pragma unroll
        for (int off = 32; off >= 1; off >>= 1)
            sum += __shfl_xor(sum, off);
        pbuf[l * 64 + lane] = p;
        rdenom[l] = __builtin_amdgcn_rcpf(sum);
    }

    // ---- fence: V done; blocks VL-read hoisting ----
    asm volatile("s_waitcnt vmcnt(0)" ::: "memory");
    __builtin_amdgcn_sched_barrier(0);

    // ---- PV: lane = d; V b32 from LDS (2-way, free) x P uniform b128 ----
    float facc[7];
#pragma unroll
    for (int l = 0; l < 7; ++l) facc[l] = 0.0f;

#pragma unroll
    for (int s4 = 0; s4 < 14; ++s4) {
        const float vv0 = VL[(s4 * 4 + 0) * 64 + lane];
        const float vv1 = VL[(s4 * 4 + 1) * 64 + lane];
        const float vv2 = VL[(s4 * 4 + 2) * 64 + lane];
        const float vv3 = VL[(s4 * 4 + 3) * 64 + lane];
#pragma unroll
        for (int l = 0; l < 7; ++l) {
            const float4 p4 = *(const float4*)(&pbuf[l * 64 + s4 * 4]);  // uniform bcast
            facc[l] = fmaf(p4.x, vv0, facc[l]);
            facc[l] = fmaf(p4.y, vv1, facc[l]);
            facc[l] = fmaf(p4.z, vv2, facc[l]);
            facc[l] = fmaf(p4.w, vv3, facc[l]);
        }
    }

    // ---- epilogue: deferred normalization + coalesced store ----
#pragma unroll
    for (int l = 0; l < 7; ++l)
        out[qbase + l * 512 + lane] = facc[l] * rdenom[l];
}

extern "C" void kernel_launch(void* const* d_in, const int* in_sizes, int n_in,
                              void* d_out, int out_size, void* d_ws, size_t ws_size,
                              hipStream_t stream) {
    const float* q    = (const float*)d_in[0];
    const float* k    = (const float*)d_in[1];
    const float* v    = (const float*)d_in[2];
    const float* mask = (const float*)d_in[3];
    float* out        = (float*)d_out;

    const int B = in_sizes[0] / (7 * 8 * 64);        // 3200
    const int nstations = in_sizes[3] / (7 * 56);    // 50

    fullattn_kernel<<<dim3(B * 8), dim3(64), 0, stream>>>(q, k, v, mask, out, nstations);
}